// Round 12
// baseline (312.318 us; speedup 1.0000x reference)
//
#include <hip/hip_runtime.h>
#include <hip/hip_bf16.h>
#include <cstddef>

// Fused 3-layer LSTM, wavefront-pipelined, swapped-operand MFMA, 16 waves.
// R12: deep skews (L0@it, L1@it-2, L2@it-4) + cross-barrier x-side register
// prefetch for mid waves (T14): the x-side operand (previous layer's h) is
// stable one full iter before use -> ds_read it during the PREVIOUS iter's
// compute; only the own-h side is read post-barrier. Trans per update 10->8
// via fused sigmoid*tanh rcp.
//
// Regions (granule = 8k x 16b = 128 shorts; lane-linear frag reads):
//   H0[3], H1[3], H2[2]; buf = 9 granules (g0 = x for L0; g1..7 = h units
//   0..55, unit u -> g 1+(u>>3) pos u&7; bias act==1.0 at g7p2 = slot 50;
//   g8 = zero pad).
// Schedules: h0(t)->H0[t%3] (x(t) staged into H0[(t-1)%3].g0);
//   h1(t)->H1[t%3] written at iter t+2; h2(t)->H2[t&1] written at iter t+4.
// Per-iter buffer map (verified race-free, write@tau / last-read@tau+2 /
// overwrite@tau+3):
//   L0:  read H0[(it+2)%3], write H0[it%3]; stage x(it+1)->H0[it%3].g0
//   L1:  use prefetched x-frags; h-side H1[it%3]; write H1[(it+1)%3];
//        fill next x from H0[(it+2)%3]
//   L2:  h-side H2[(it+1)&1]; write H2[it&1]; fill next x from H1[it%3]
//   orphan (tile12 x3, unprefetched): L1-x H0[(it+1)%3], L2-x H1[(it+2)%3]
// One s_barrier per iter, NITER=260. 2-term weight split, acts RNE bf16.

#define T_STEPS 256
#define NITER   260
#define BTOT    4096
#define NTHR    1024
#define GS      128
#define BUFSZ   (9 * GS)

typedef __attribute__((ext_vector_type(8))) short short8;
typedef __attribute__((ext_vector_type(4))) float f32x4;

#define BAR() do { \
    asm volatile("s_waitcnt lgkmcnt(0)" ::: "memory"); \
    __builtin_amdgcn_sched_barrier(0); \
    __builtin_amdgcn_s_barrier(); \
    __builtin_amdgcn_sched_barrier(0); \
} while (0)

__device__ __forceinline__ unsigned short f2bf(float x) {     // RNE
    union { __hip_bfloat16 b; unsigned short s; } u;
    u.b = __float2bfloat16(x);
    return u.s;
}
__device__ __forceinline__ float bf2f(unsigned short s) {
    union { unsigned u; float f; } v; v.u = (unsigned)s << 16; return v.f;
}

// 8-trans cell update: sigma(i)tanh(g) and sigma(o)tanh(c) share one rcp each.
// sigma(i)tanh(g) = (e2g - 1) * rcp((1+e_i)(1+e2g)); clamps keep e2g/e2c
// finite so inf/inf NaN is impossible (inf only in the denominator -> 0).
__device__ __forceinline__ float cell_upd(f32x4 g, float& cst) {
    const float K1 = 1.4426950408889634f;   // log2(e)
    const float K2 = 2.8853900817779268f;   // 2*log2(e)
    float gc  = fminf(fmaxf(g[2], -30.0f), 30.0f);
    float eg  = __builtin_amdgcn_exp2f(K2 * gc);
    float ei  = __builtin_amdgcn_exp2f(-K1 * g[0]);
    float itg = (eg - 1.0f) * __builtin_amdgcn_rcpf((1.0f + ei) * (1.0f + eg));
    float ef  = __builtin_amdgcn_exp2f(-K1 * g[1]);
    float fg  = __builtin_amdgcn_rcpf(1.0f + ef);
    float c   = fmaf(fg, cst, itg);
    cst = c;
    float cc  = fminf(fmaxf(c, -30.0f), 30.0f);
    float ec  = __builtin_amdgcn_exp2f(K2 * cc);
    float eo  = __builtin_amdgcn_exp2f(-K1 * g[3]);
    return (ec - 1.0f) * __builtin_amdgcn_rcpf((1.0f + eo) * (1.0f + ec));
}

// Weights -> (hi,lo) frags. Row N' = (T0+q)*16 + (lane&15), k = ks*32+kg*8+e.
// L0M: [w_ih(8)@k0-7 | w_hh@k8-57 | bias@58]; MID: [w_ih@k0-49 | bias@50 |
// zeros | w_hh@k64-113 | zeros].
template<bool L0M, int NT, int KS>
__device__ __forceinline__ void load_wb(int T0, int lane,
    const float* __restrict__ w_ih, const float* __restrict__ w_hh,
    const float* __restrict__ b_ih, const float* __restrict__ b_hh,
    short8 (&Wh)[NT][KS], short8 (&Wl)[NT][KS])
{
    const int m = lane & 15, kg = lane >> 4;
    #pragma unroll
    for (int q = 0; q < NT; ++q) {
        int gp = (T0 + q) * 16 + m;
        int gr = (gp < 200) ? ((gp & 3) * 50 + (gp >> 2)) : -1;
        float bias = (gr >= 0) ? (b_ih[gr] + b_hh[gr]) : 0.0f;
        #pragma unroll
        for (int ks = 0; ks < KS; ++ks)
            #pragma unroll
            for (int e = 0; e < 8; ++e) {
                int k = ks * 32 + kg * 8 + e;
                float v = 0.0f;
                if (gr >= 0) {
                    if (L0M) {
                        if (k < 8) v = w_ih[gr * 8 + k];
                        else if (k < 58) v = w_hh[gr * 50 + (k - 8)];
                        else if (k == 58) v = bias;
                    } else {
                        if (k < 50) v = w_ih[gr * 50 + k];
                        else if (k == 50) v = bias;
                        else if (k >= 64 && k < 114) v = w_hh[gr * 50 + (k - 64)];
                    }
                }
                unsigned short hb = f2bf(v);
                Wh[q][ks][e] = (short)hb;
                Wl[q][ks][e] = (short)f2bf(v - bf2f(hb));
            }
    }
}

// L0 wave: NT=4 tiles, skew 0. XST: stage x(it+1) -> H0[it%3].g0.
template<int T0, bool XST>
__device__ void role_l0(int lane, int b0, const float* __restrict__ xf,
    const float* w_ih, const float* w_hh, const float* b_ih, const float* b_hh,
    short (*H0)[BUFSZ])
{
    short8 Wh[4][2], Wl[4][2];
    load_wb<true, 4, 2>(T0, lane, w_ih, w_hh, b_ih, b_hh, Wh, Wl);
    float cst[4] = {0.0f, 0.0f, 0.0f, 0.0f};
    const int b = lane & 15, kg = lane >> 4;

    for (int it = 0; it < NITER; ++it) {
        const bool stg = XST && (kg == 0) && (it + 1 < T_STEPS);
        float xs[8];
        if (stg) {
            const float* xr = &xf[((size_t)(b0 + b) * T_STEPS + (it + 1)) * 8];
            *(float4*)&xs[0] = *(const float4*)xr;
            *(float4*)&xs[4] = *(const float4*)(xr + 4);
        }
        if (it < T_STEPS) {
            const short* rb = H0[(it + 2) % 3];
            short*       wb = H0[it % 3];
            short8 A0 = *(const short8*)&rb[kg * GS + b * 8];
            short8 A1 = *(const short8*)&rb[(4 + kg) * GS + b * 8];
            f32x4 acc[4];
            #pragma unroll
            for (int q = 0; q < 4; ++q) acc[q] = (f32x4){0.0f, 0.0f, 0.0f, 0.0f};
            #pragma unroll
            for (int q = 0; q < 4; ++q)
                acc[q] = __builtin_amdgcn_mfma_f32_16x16x32_bf16(Wh[q][0], A0, acc[q], 0, 0, 0);
            #pragma unroll
            for (int q = 0; q < 4; ++q)
                acc[q] = __builtin_amdgcn_mfma_f32_16x16x32_bf16(Wh[q][1], A1, acc[q], 0, 0, 0);
            #pragma unroll
            for (int q = 0; q < 4; ++q)
                acc[q] = __builtin_amdgcn_mfma_f32_16x16x32_bf16(Wl[q][0], A0, acc[q], 0, 0, 0);
            #pragma unroll
            for (int q = 0; q < 4; ++q)
                acc[q] = __builtin_amdgcn_mfma_f32_16x16x32_bf16(Wl[q][1], A1, acc[q], 0, 0, 0);
            #pragma unroll
            for (int q = 0; q < 4; ++q) {
                int u = (T0 + q) * 4 + kg;                    // <= 47
                float h = cell_upd(acc[q], cst[q]);
                wb[(1 + (u >> 3)) * GS + b * 8 + (u & 7)] = (short)f2bf(h);
            }
        }
        if (stg) {
            short8 hi;
            #pragma unroll
            for (int e = 0; e < 8; ++e) hi[e] = (short)f2bf(xs[e]);
            *(short8*)&H0[it % 3][b * 8] = hi;
        }
        BAR();
    }
}

// Mid wave, NT=2, x-side prefetched across the barrier (ping-pong regs).
// LASTL: L2 (skew 4, hf at t=255); else L1 (skew 2).
template<int T0, bool LASTL>
__device__ void role_mid(int lane,
    const float* w_ih, const float* w_hh, const float* b_ih, const float* b_hh,
    short (*H0)[BUFSZ], short (*H1)[BUFSZ], short (*H2)[BUFSZ], float* hfp)
{
    constexpr int SKEW = LASTL ? 4 : 2;
    short8 Wh[2][4], Wl[2][4];
    load_wb<false, 2, 4>(T0, lane, w_ih, w_hh, b_ih, b_hh, Wh, Wl);
    float cst[2] = {0.0f, 0.0f};
    const int b = lane & 15, kg = lane >> 4;
    short8 AxA[2], AxB[2];

    auto step = [&](int it, short8 (&use)[2], short8 (&fill)[2]) {
        const int t = it - SKEW;
        const short* hsb = LASTL ? H2[(it + 1) & 1] : H1[it % 3];
        short*       wb  = LASTL ? H2[it & 1]       : H1[(it + 1) % 3];
        const short* fsrc= LASTL ? H1[it % 3]       : H0[(it + 2) % 3];
        if (0 <= t && t < T_STEPS) {
            short8 Ah0 = *(const short8*)&hsb[(1 + kg) * GS + b * 8];
            short8 Ah1 = *(const short8*)&hsb[(5 + kg) * GS + b * 8];
            f32x4 accA[2], accB[2];
            #pragma unroll
            for (int q = 0; q < 2; ++q) {
                accA[q] = (f32x4){0.0f, 0.0f, 0.0f, 0.0f};
                accB[q] = (f32x4){0.0f, 0.0f, 0.0f, 0.0f};
            }
            // x-part first: operands already in registers (prefetched)
            #pragma unroll
            for (int q = 0; q < 2; ++q)
                accA[q] = __builtin_amdgcn_mfma_f32_16x16x32_bf16(Wh[q][0], use[0], accA[q], 0, 0, 0);
            #pragma unroll
            for (int q = 0; q < 2; ++q)
                accA[q] = __builtin_amdgcn_mfma_f32_16x16x32_bf16(Wh[q][1], use[1], accA[q], 0, 0, 0);
            #pragma unroll
            for (int q = 0; q < 2; ++q)
                accA[q] = __builtin_amdgcn_mfma_f32_16x16x32_bf16(Wl[q][0], use[0], accA[q], 0, 0, 0);
            #pragma unroll
            for (int q = 0; q < 2; ++q)
                accA[q] = __builtin_amdgcn_mfma_f32_16x16x32_bf16(Wl[q][1], use[1], accA[q], 0, 0, 0);
            // h-part (ds_reads above covered by compiler-inserted lgkm waits)
            #pragma unroll
            for (int q = 0; q < 2; ++q)
                accB[q] = __builtin_amdgcn_mfma_f32_16x16x32_bf16(Wh[q][2], Ah0, accB[q], 0, 0, 0);
            #pragma unroll
            for (int q = 0; q < 2; ++q)
                accB[q] = __builtin_amdgcn_mfma_f32_16x16x32_bf16(Wh[q][3], Ah1, accB[q], 0, 0, 0);
            #pragma unroll
            for (int q = 0; q < 2; ++q)
                accB[q] = __builtin_amdgcn_mfma_f32_16x16x32_bf16(Wl[q][2], Ah0, accB[q], 0, 0, 0);
            #pragma unroll
            for (int q = 0; q < 2; ++q)
                accB[q] = __builtin_amdgcn_mfma_f32_16x16x32_bf16(Wl[q][3], Ah1, accB[q], 0, 0, 0);
            #pragma unroll
            for (int q = 0; q < 2; ++q) {
                int u = (T0 + q) * 4 + kg;                    // <= 47
                float h = cell_upd(accA[q] + accB[q], cst[q]);
                wb[(1 + (u >> 3)) * GS + b * 8 + (u & 7)] = (short)f2bf(h);
                if (LASTL && t == T_STEPS - 1) hfp[b * 56 + u] = h;
            }
        }
        const int tn = it + 1 - SKEW;
        if (0 <= tn && tn < T_STEPS) {
            fill[0] = *(const short8*)&fsrc[(1 + kg) * GS + b * 8];
            fill[1] = *(const short8*)&fsrc[(5 + kg) * GS + b * 8];
        }
    };

    for (int it = 0; it < NITER; it += 2) {
        step(it, AxA, AxB);
        BAR();
        step(it + 1, AxB, AxA);
        BAR();
    }
}

// Orphan: tile 12 of L0 (skew 0), L1 (skew 2), L2 (skew 4); units 48,49
// (guard kg<2). Unprefetched; reads are race-free under the 3-buffer
// schedules (see header map).
__device__ void role_orphan(int lane,
    const float* w_ih0, const float* w_hh0, const float* b_ih0, const float* b_hh0,
    const float* w_ih1, const float* w_hh1, const float* b_ih1, const float* b_hh1,
    const float* w_ih2, const float* w_hh2, const float* b_ih2, const float* b_hh2,
    short (*H0)[BUFSZ], short (*H1)[BUFSZ], short (*H2)[BUFSZ], float* hfp)
{
    short8 W0h[1][2], W0l[1][2], W1h[1][4], W1l[1][4], W2h[1][4], W2l[1][4];
    load_wb<true, 1, 2>(12, lane, w_ih0, w_hh0, b_ih0, b_hh0, W0h, W0l);
    load_wb<false, 1, 4>(12, lane, w_ih1, w_hh1, b_ih1, b_hh1, W1h, W1l);
    load_wb<false, 1, 4>(12, lane, w_ih2, w_hh2, b_ih2, b_hh2, W2h, W2l);
    float c0 = 0.0f, c1 = 0.0f, c2 = 0.0f;
    const int b = lane & 15, kg = lane >> 4;

    for (int it = 0; it < NITER; ++it) {
        // L0 phase, t0 = it
        if (it < T_STEPS) {
            const short* rb = H0[(it + 2) % 3];
            short8 A0 = *(const short8*)&rb[kg * GS + b * 8];
            short8 A1 = *(const short8*)&rb[(4 + kg) * GS + b * 8];
            f32x4 a = (f32x4){0.0f, 0.0f, 0.0f, 0.0f};
            a = __builtin_amdgcn_mfma_f32_16x16x32_bf16(W0h[0][0], A0, a, 0, 0, 0);
            a = __builtin_amdgcn_mfma_f32_16x16x32_bf16(W0h[0][1], A1, a, 0, 0, 0);
            a = __builtin_amdgcn_mfma_f32_16x16x32_bf16(W0l[0][0], A0, a, 0, 0, 0);
            a = __builtin_amdgcn_mfma_f32_16x16x32_bf16(W0l[0][1], A1, a, 0, 0, 0);
            if (kg < 2) {
                int u = 48 + kg;
                float h = cell_upd(a, c0);
                H0[it % 3][(1 + (u >> 3)) * GS + b * 8 + (u & 7)] = (short)f2bf(h);
            }
        }
        // L1 phase, t1 = it-2; x-side h0(it-2) in H0[(it+1)%3] (safe: its
        // next overwrite is h0(it+1) written at iter it+1)
        int t1 = it - 2;
        if ((unsigned)t1 < T_STEPS) {
            const short* xb = H0[(it + 1) % 3];
            const short* hb = H1[it % 3];
            short8 X0 = *(const short8*)&xb[(1 + kg) * GS + b * 8];
            short8 X1 = *(const short8*)&xb[(5 + kg) * GS + b * 8];
            short8 Hh0 = *(const short8*)&hb[(1 + kg) * GS + b * 8];
            short8 Hh1 = *(const short8*)&hb[(5 + kg) * GS + b * 8];
            f32x4 a = (f32x4){0.0f, 0.0f, 0.0f, 0.0f};
            a = __builtin_amdgcn_mfma_f32_16x16x32_bf16(W1h[0][0], X0, a, 0, 0, 0);
            a = __builtin_amdgcn_mfma_f32_16x16x32_bf16(W1h[0][1], X1, a, 0, 0, 0);
            a = __builtin_amdgcn_mfma_f32_16x16x32_bf16(W1h[0][2], Hh0, a, 0, 0, 0);
            a = __builtin_amdgcn_mfma_f32_16x16x32_bf16(W1h[0][3], Hh1, a, 0, 0, 0);
            a = __builtin_amdgcn_mfma_f32_16x16x32_bf16(W1l[0][0], X0, a, 0, 0, 0);
            a = __builtin_amdgcn_mfma_f32_16x16x32_bf16(W1l[0][1], X1, a, 0, 0, 0);
            a = __builtin_amdgcn_mfma_f32_16x16x32_bf16(W1l[0][2], Hh0, a, 0, 0, 0);
            a = __builtin_amdgcn_mfma_f32_16x16x32_bf16(W1l[0][3], Hh1, a, 0, 0, 0);
            if (kg < 2) {
                int u = 48 + kg;
                float h = cell_upd(a, c1);
                H1[(it + 1) % 3][(1 + (u >> 3)) * GS + b * 8 + (u & 7)] = (short)f2bf(h);
            }
        }
        // L2 phase, t2 = it-4; x-side h1(it-4) in H1[(it+2)%3] (next
        // overwrite h1(it+2) at iter it+4)
        int t2 = it - 4;
        if ((unsigned)t2 < T_STEPS) {
            const short* xb = H1[(it + 2) % 3];
            const short* hb = H2[(it + 1) & 1];
            short8 X0 = *(const short8*)&xb[(1 + kg) * GS + b * 8];
            short8 X1 = *(const short8*)&xb[(5 + kg) * GS + b * 8];
            short8 Hh0 = *(const short8*)&hb[(1 + kg) * GS + b * 8];
            short8 Hh1 = *(const short8*)&hb[(5 + kg) * GS + b * 8];
            f32x4 a = (f32x4){0.0f, 0.0f, 0.0f, 0.0f};
            a = __builtin_amdgcn_mfma_f32_16x16x32_bf16(W2h[0][0], X0, a, 0, 0, 0);
            a = __builtin_amdgcn_mfma_f32_16x16x32_bf16(W2h[0][1], X1, a, 0, 0, 0);
            a = __builtin_amdgcn_mfma_f32_16x16x32_bf16(W2h[0][2], Hh0, a, 0, 0, 0);
            a = __builtin_amdgcn_mfma_f32_16x16x32_bf16(W2h[0][3], Hh1, a, 0, 0, 0);
            a = __builtin_amdgcn_mfma_f32_16x16x32_bf16(W2l[0][0], X0, a, 0, 0, 0);
            a = __builtin_amdgcn_mfma_f32_16x16x32_bf16(W2l[0][1], X1, a, 0, 0, 0);
            a = __builtin_amdgcn_mfma_f32_16x16x32_bf16(W2l[0][2], Hh0, a, 0, 0, 0);
            a = __builtin_amdgcn_mfma_f32_16x16x32_bf16(W2l[0][3], Hh1, a, 0, 0, 0);
            if (kg < 2) {
                int u = 48 + kg;
                float h = cell_upd(a, c2);
                H2[it & 1][(1 + (u >> 3)) * GS + b * 8 + (u & 7)] = (short)f2bf(h);
                if (t2 == T_STEPS - 1) hfp[b * 56 + u] = h;
            }
        }
        BAR();
    }
}

__global__ __launch_bounds__(NTHR) void lstm_fused(
    const float* __restrict__ xf,
    const float* w_ih0, const float* w_hh0, const float* b_ih0, const float* b_hh0,
    const float* w_ih1, const float* w_hh1, const float* b_ih1, const float* b_hh1,
    const float* w_ih2, const float* w_hh2, const float* b_ih2, const float* b_hh2,
    const float* __restrict__ w_fc, const float* __restrict__ b_fc,
    float* __restrict__ out)
{
    __shared__ __align__(16) short H0[3][BUFSZ];
    __shared__ __align__(16) short H1[3][BUFSZ];
    __shared__ __align__(16) short H2[2][BUFSZ];
    __shared__ __align__(16) float hf[16 * 56];

    const int tid  = threadIdx.x;
    const int lane = tid & 63;
    const int wid  = tid >> 6;
    const int b0   = blockIdx.x * 16;

    for (int i = tid; i < 3 * BUFSZ; i += NTHR) { ((short*)H0)[i] = 0; ((short*)H1)[i] = 0; }
    for (int i = tid; i < 2 * BUFSZ; i += NTHR) ((short*)H2)[i] = 0;
    __syncthreads();

    // bias act columns (g7 p2 = slot 50) = 1.0 in all 8 buffers
    if (tid < 128) {
        int bufi = tid >> 4, b = tid & 15;
        short* bp = (bufi < 3) ? H0[bufi]
                  : (bufi < 6) ? H1[bufi - 3] : H2[bufi - 6];
        bp[7 * GS + b * 8 + 2] = (short)0x3F80;
    }
    // x(0) -> H0[2].g0  (L0 at it=0 reads H0[(0+2)%3] = H0[2])
    if (tid < 16) {
        int b = tid;
        #pragma unroll
        for (int j = 0; j < 8; ++j) {
            float v = xf[((size_t)(b0 + b) * T_STEPS + 0) * 8 + j];
            H0[2][b * 8 + j] = (short)f2bf(v);
        }
    }
    __syncthreads();

    if      (wid == 0)  role_l0<0, false>(lane, b0, xf, w_ih0, w_hh0, b_ih0, b_hh0, H0);
    else if (wid == 1)  role_l0<4, false>(lane, b0, xf, w_ih0, w_hh0, b_ih0, b_hh0, H0);
    else if (wid == 2)  role_l0<8, true >(lane, b0, xf, w_ih0, w_hh0, b_ih0, b_hh0, H0);
    else if (wid == 3)  role_orphan(lane,
                            w_ih0, w_hh0, b_ih0, b_hh0,
                            w_ih1, w_hh1, b_ih1, b_hh1,
                            w_ih2, w_hh2, b_ih2, b_hh2, H0, H1, H2, hf);
    else if (wid == 4)  role_mid<0,  false>(lane, w_ih1, w_hh1, b_ih1, b_hh1, H0, H1, H2, nullptr);
    else if (wid == 5)  role_mid<2,  false>(lane, w_ih1, w_hh1, b_ih1, b_hh1, H0, H1, H2, nullptr);
    else if (wid == 6)  role_mid<4,  false>(lane, w_ih1, w_hh1, b_ih1, b_hh1, H0, H1, H2, nullptr);
    else if (wid == 7)  role_mid<6,  false>(lane, w_ih1, w_hh1, b_ih1, b_hh1, H0, H1, H2, nullptr);
    else if (wid == 8)  role_mid<8,  false>(lane, w_ih1, w_hh1, b_ih1, b_hh1, H0, H1, H2, nullptr);
    else if (wid == 9)  role_mid<10, false>(lane, w_ih1, w_hh1, b_ih1, b_hh1, H0, H1, H2, nullptr);
    else if (wid == 10) role_mid<0,  true >(lane, w_ih2, w_hh2, b_ih2, b_hh2, H0, H1, H2, hf);
    else if (wid == 11) role_mid<2,  true >(lane, w_ih2, w_hh2, b_ih2, b_hh2, H0, H1, H2, hf);
    else if (wid == 12) role_mid<4,  true >(lane, w_ih2, w_hh2, b_ih2, b_hh2, H0, H1, H2, hf);
    else if (wid == 13) role_mid<6,  true >(lane, w_ih2, w_hh2, b_ih2, b_hh2, H0, H1, H2, hf);
    else if (wid == 14) role_mid<8,  true >(lane, w_ih2, w_hh2, b_ih2, b_hh2, H0, H1, H2, hf);
    else                role_mid<10, true >(lane, w_ih2, w_hh2, b_ih2, b_hh2, H0, H1, H2, hf);

    __syncthreads();

    if (tid < 96) {
        int b = tid / 6, o = tid - b * 6;
        float a = b_fc[o];
        #pragma unroll
        for (int n = 0; n < 50; ++n)
            a = fmaf(w_fc[o * 50 + n], hf[b * 56 + n], a);
        out[(size_t)(b0 + b) * 6 + o] = a;
    }
}

extern "C" void kernel_launch(void* const* d_in, const int* in_sizes, int n_in,
                              void* d_out, int out_size, void* d_ws, size_t ws_size,
                              hipStream_t stream) {
    (void)in_sizes; (void)n_in; (void)d_ws; (void)ws_size; (void)out_size;

    const float* x     = (const float*)d_in[0];
    const float* w_ih0 = (const float*)d_in[1];
    const float* w_hh0 = (const float*)d_in[2];
    const float* b_ih0 = (const float*)d_in[3];
    const float* b_hh0 = (const float*)d_in[4];
    const float* w_ih1 = (const float*)d_in[5];
    const float* w_hh1 = (const float*)d_in[6];
    const float* b_ih1 = (const float*)d_in[7];
    const float* b_hh1 = (const float*)d_in[8];
    const float* w_ih2 = (const float*)d_in[9];
    const float* w_hh2 = (const float*)d_in[10];
    const float* b_ih2 = (const float*)d_in[11];
    const float* b_hh2 = (const float*)d_in[12];
    const float* w_fc  = (const float*)d_in[13];
    const float* b_fc  = (const float*)d_in[14];
    float* out = (float*)d_out;

    lstm_fused<<<dim3(BTOT / 16), dim3(NTHR), 0, stream>>>(
        x, w_ih0, w_hh0, b_ih0, b_hh0, w_ih1, w_hh1, b_ih1, b_hh1,
        w_ih2, w_hh2, b_ih2, b_hh2, w_fc, b_fc, out);
}